// Round 3
// baseline (260.801 us; speedup 1.0000x reference)
//
#include <hip/hip_runtime.h>

// OsuRatingSystem: out[b] = dot(player_table[pidx[b]], map_table[midx[b]]), D=64.
//
// Strategy: the 205 MB of map-table re-reads (5x avg reuse, 51 MB table) are
// recoverable only by creating temporal locality explicitly. Bucket samples by
// map index (4096 buckets ~= 12.5 KB of map rows each), process in bucket order
// with chunked XCD mapping so each bucket's map slice stays in one XCD's L2.
//
// Pipeline (all on stream, graph-capture safe, no host sync):
//   k_zero -> k_hist -> k_scan -> k_scatter -> k_process

#define NB 4096

typedef float f4 __attribute__((ext_vector_type(4)));

__global__ void k_zero(int* __restrict__ hist) {
    int t = blockIdx.x * blockDim.x + threadIdx.x;
    if (t < NB) hist[t] = 0;
}

__global__ __launch_bounds__(256) void k_hist(const int* __restrict__ midx,
                                              int* __restrict__ hist, int n, int shift) {
    int i = blockIdx.x * blockDim.x + threadIdx.x;
    int stride = gridDim.x * blockDim.x;
    for (; i < n; i += stride)
        atomicAdd(&hist[midx[i] >> shift], 1);
}

// Exclusive scan of hist[NB] -> cursor[NB]. One workgroup, 1024 threads x 4 elems.
__global__ __launch_bounds__(1024) void k_scan(const int* __restrict__ hist,
                                               int* __restrict__ cursor) {
    __shared__ int lds[1024];
    int t = threadIdx.x;
    int4 h = *reinterpret_cast<const int4*>(hist + t * 4);
    int s0 = h.x, s1 = s0 + h.y, s2 = s1 + h.z, s3 = s2 + h.w;
    lds[t] = s3;
    __syncthreads();
    for (int off = 1; off < 1024; off <<= 1) {
        int x = (t >= off) ? lds[t - off] : 0;
        __syncthreads();
        lds[t] += x;
        __syncthreads();
    }
    int prefix = (t > 0) ? lds[t - 1] : 0;
    int4 e;
    e.x = prefix; e.y = prefix + s0; e.z = prefix + s1; e.w = prefix + s2;
    *reinterpret_cast<int4*>(cursor + t * 4) = e;
}

__global__ __launch_bounds__(256) void k_scatter(
    const int* __restrict__ pidx, const int* __restrict__ midx,
    int* __restrict__ cursor,
    int* __restrict__ rp, int* __restrict__ rm, int* __restrict__ rs,
    int n, int shift) {
    int i = blockIdx.x * blockDim.x + threadIdx.x;
    int stride = gridDim.x * blockDim.x;
    for (; i < n; i += stride) {
        int mi = midx[i];
        int pos = atomicAdd(&cursor[mi >> shift], 1);
        rp[pos] = pidx[i];
        rm[pos] = mi;
        rs[pos] = i;
    }
}

// 16 lanes per record; records are in bucket (map-sorted) order.
__global__ __launch_bounds__(256) void k_process(
    const int* __restrict__ rp, const int* __restrict__ rm, const int* __restrict__ rs,
    const float* __restrict__ ptab, const float* __restrict__ mtab,
    float* __restrict__ out, int n, int q, int r) {
    // Bijective round-robin -> chunked XCD transform (m204): consecutive
    // records (same bucket) process on the SAME XCD so the bucket's map rows
    // stay L2-resident.
    int o = blockIdx.x;
    int xcd = o & 7, idx = o >> 3;
    int wg = (xcd < r) ? xcd * (q + 1) + idx : r * (q + 1) + (xcd - r) * q + idx;

    int tid = wg * 256 + (int)threadIdx.x;
    int sample = tid >> 4;
    int lane4 = tid & 15;
    if (sample >= n) return;

    int pi = rp[sample];
    int mi = rm[sample];

    f4 pv = *reinterpret_cast<const f4*>(ptab + (size_t)pi * 64 + (size_t)lane4 * 4);
    f4 mv = *reinterpret_cast<const f4*>(mtab + (size_t)mi * 64 + (size_t)lane4 * 4);

    float s = pv.x * mv.x + pv.y * mv.y + pv.z * mv.z + pv.w * mv.w;

    s += __shfl_xor(s, 1, 16);
    s += __shfl_xor(s, 2, 16);
    s += __shfl_xor(s, 4, 16);
    s += __shfl_xor(s, 8, 16);

    if (lane4 == 0) out[rs[sample]] = s;
}

// Fallback (round-1 kernel) if ws is too small.
__global__ __launch_bounds__(256) void k_direct(
    const int* __restrict__ pidx, const int* __restrict__ midx,
    const float* __restrict__ ptab, const float* __restrict__ mtab,
    float* __restrict__ out, int n) {
    int tid = blockIdx.x * blockDim.x + threadIdx.x;
    int sample = tid >> 4;
    int lane4 = tid & 15;
    if (sample >= n) return;
    int pi = pidx[sample];
    int mi = midx[sample];
    f4 pv = *reinterpret_cast<const f4*>(ptab + (size_t)pi * 64 + (size_t)lane4 * 4);
    f4 mv = *reinterpret_cast<const f4*>(mtab + (size_t)mi * 64 + (size_t)lane4 * 4);
    float s = pv.x * mv.x + pv.y * mv.y + pv.z * mv.z + pv.w * mv.w;
    s += __shfl_xor(s, 1, 16);
    s += __shfl_xor(s, 2, 16);
    s += __shfl_xor(s, 4, 16);
    s += __shfl_xor(s, 8, 16);
    if (lane4 == 0) out[sample] = s;
}

extern "C" void kernel_launch(void* const* d_in, const int* in_sizes, int n_in,
                              void* d_out, int out_size, void* d_ws, size_t ws_size,
                              hipStream_t stream) {
    const int*   pidx = (const int*)d_in[0];
    const int*   midx = (const int*)d_in[1];
    const float* ptab = (const float*)d_in[2];
    const float* mtab = (const float*)d_in[3];
    float*       out  = (float*)d_out;

    int n = in_sizes[0];                 // BATCH
    int nmaps = in_sizes[3] / 64;        // map table rows

    size_t need = (size_t)(2 * NB + 3 * (size_t)n) * sizeof(int);
    if (ws_size < need) {
        int total = n * 16;
        k_direct<<<(total + 255) / 256, 256, 0, stream>>>(pidx, midx, ptab, mtab, out, n);
        return;
    }

    // shift so that (nmaps-1)>>shift < NB
    int shift = 0;
    while (((nmaps - 1) >> shift) >= NB) shift++;

    int* hist   = (int*)d_ws;
    int* cursor = hist + NB;
    int* rp     = cursor + NB;
    int* rm     = rp + n;
    int* rs     = rm + n;

    k_zero<<<(NB + 255) / 256, 256, 0, stream>>>(hist);
    k_hist<<<2048, 256, 0, stream>>>(midx, hist, n, shift);
    k_scan<<<1, 1024, 0, stream>>>(hist, cursor);
    k_scatter<<<2048, 256, 0, stream>>>(pidx, midx, cursor, rp, rm, rs, n, shift);

    int total = n * 16;
    int nwg = (total + 255) / 256;
    int q = nwg / 8, r = nwg % 8;
    k_process<<<nwg, 256, 0, stream>>>(rp, rm, rs, ptab, mtab, out, n, q, r);
}

// Round 4
// 183.582 us; speedup vs baseline: 1.4206x; 1.4206x over previous
//
#include <hip/hip_runtime.h>

// OsuRatingSystem: out[b] = dot(player_table[pidx[b]], map_table[midx[b]]), D=64.
//
// Multi-pass map-range filtering: C=4 passes; pass p touches only samples whose
// map index falls in chunk p (~12.75 MB of map rows). Within a pass the map
// working set is small enough to stay L2/L3-resident, recovering the ~205 MB
// of map re-reads that the single-pass version sends to HBM. No sorting, no
// atomics, no materialized permutation (R3 showed those cost more than they buy).
// Overhead: index arrays re-read each pass (+~24 MB), out partial-line writes
// (absorbed by L3; out is only 4 MB).

#define NCHUNKS 4

typedef float f4 __attribute__((ext_vector_type(4)));

__global__ __launch_bounds__(256) void osu_pass_kernel(
    const int* __restrict__ pidx,
    const int* __restrict__ midx,
    const float* __restrict__ ptab,
    const float* __restrict__ mtab,
    float* __restrict__ out,
    int n, int lo, int hi)
{
    int tid = blockIdx.x * blockDim.x + threadIdx.x;
    int sample = tid >> 4;   // 16 lanes per sample
    int lane4  = tid & 15;
    if (sample >= n) return;

    int mi = midx[sample];
    if (mi < lo || mi >= hi) return;   // not this pass's chunk

    int pi = pidx[sample];

    f4 pv = *reinterpret_cast<const f4*>(ptab + (size_t)pi * 64 + (size_t)lane4 * 4);
    f4 mv = *reinterpret_cast<const f4*>(mtab + (size_t)mi * 64 + (size_t)lane4 * 4);

    float s = pv.x * mv.x + pv.y * mv.y + pv.z * mv.z + pv.w * mv.w;

    s += __shfl_xor(s, 1, 16);
    s += __shfl_xor(s, 2, 16);
    s += __shfl_xor(s, 4, 16);
    s += __shfl_xor(s, 8, 16);

    if (lane4 == 0) out[sample] = s;
}

extern "C" void kernel_launch(void* const* d_in, const int* in_sizes, int n_in,
                              void* d_out, int out_size, void* d_ws, size_t ws_size,
                              hipStream_t stream) {
    const int*   pidx = (const int*)d_in[0];
    const int*   midx = (const int*)d_in[1];
    const float* ptab = (const float*)d_in[2];
    const float* mtab = (const float*)d_in[3];
    float*       out  = (float*)d_out;

    int n = in_sizes[0];              // BATCH
    int nmaps = in_sizes[3] / 64;     // map table rows

    int total = n * 16;
    int block = 256;
    int grid = (total + block - 1) / block;

    int csz = (nmaps + NCHUNKS - 1) / NCHUNKS;
    for (int c = 0; c < NCHUNKS; ++c) {
        int lo = c * csz;
        int hi = (lo + csz < nmaps) ? lo + csz : nmaps;
        if (lo >= hi) continue;
        osu_pass_kernel<<<grid, block, 0, stream>>>(pidx, midx, ptab, mtab, out, n, lo, hi);
    }
}

// Round 5
// 76.853 us; speedup vs baseline: 3.3935x; 2.3887x over previous
//
#include <hip/hip_runtime.h>

// OsuRatingSystem: out[b] = dot(player_table[pidx[b]], map_table[midx[b]]), D=64.
// Memory-bound random gather at the no-locality traffic floor (~476 MB).
// R2 (nt hints), R3 (bucket sort), R4 (multi-pass filtering) all regressed:
// locality cannot be created cheaper than it's worth for uniform-random indices.
// This round: persistent-ish grid + 2-deep unroll for cross-sample MLP,
// amortized launch preamble. Same traffic, better execution efficiency.

typedef float f4 __attribute__((ext_vector_type(4)));

__global__ __launch_bounds__(256) void osu_rating_dot_kernel(
    const int* __restrict__ pidx,
    const int* __restrict__ midx,
    const float* __restrict__ ptab,
    const float* __restrict__ mtab,
    float* __restrict__ out,
    int n)
{
    const int lane4 = threadIdx.x & 15;                      // which float4 of the row
    const int group = (blockIdx.x * blockDim.x + threadIdx.x) >> 4;
    const int ngroups = (gridDim.x * blockDim.x) >> 4;

    #pragma unroll 2
    for (int s = group; s < n; s += ngroups) {
        int pi = pidx[s];
        int mi = midx[s];

        f4 pv = *reinterpret_cast<const f4*>(ptab + (size_t)pi * 64 + (size_t)lane4 * 4);
        f4 mv = *reinterpret_cast<const f4*>(mtab + (size_t)mi * 64 + (size_t)lane4 * 4);

        float r = pv.x * mv.x + pv.y * mv.y + pv.z * mv.z + pv.w * mv.w;

        r += __shfl_xor(r, 1, 16);
        r += __shfl_xor(r, 2, 16);
        r += __shfl_xor(r, 4, 16);
        r += __shfl_xor(r, 8, 16);

        if (lane4 == 0) out[s] = r;
    }
}

extern "C" void kernel_launch(void* const* d_in, const int* in_sizes, int n_in,
                              void* d_out, int out_size, void* d_ws, size_t ws_size,
                              hipStream_t stream) {
    const int*   pidx = (const int*)d_in[0];
    const int*   midx = (const int*)d_in[1];
    const float* ptab = (const float*)d_in[2];
    const float* mtab = (const float*)d_in[3];
    float*       out  = (float*)d_out;

    int n = in_sizes[0];              // BATCH = 1,000,000

    // 8192 blocks = 2M threads = 128K groups; each group handles ~8 samples.
    int block = 256;
    int grid = 8192;

    osu_rating_dot_kernel<<<grid, block, 0, stream>>>(pidx, midx, ptab, mtab, out, n);
}